// Round 15
// baseline (85.114 us; speedup 1.0000x reference)
//
#include <hip/hip_runtime.h>
#include <hip/hip_bf16.h>
#include <math.h>

// Problem constants
#define B_ 4
#define T_ 4096
#define C_ 1024
#define H_ 128
#define SCALE 0.08838834764831845f       // 1/sqrt(128)
#define SCL2  0.12752934464f             // SCALE * log2(e)

typedef __attribute__((ext_vector_type(8))) short bf16x8;
typedef __attribute__((ext_vector_type(4))) float f32x4;

__device__ __forceinline__ unsigned short f2bf(float f) {
    union { float f; unsigned u; } x; x.f = f;
    unsigned r = x.u + 0x7FFF + ((x.u >> 16) & 1);
    return (unsigned short)(r >> 16);
}
__device__ __forceinline__ float bf2f(unsigned short u) {
    union { unsigned u; float f; } x; x.u = ((unsigned)u) << 16;
    return x.f;
}
__device__ __forceinline__ unsigned cvt_pk_bf16(float a, float b) {
    unsigned r;
    asm("v_cvt_pk_bf16_f32 %0, %1, %2" : "=v"(r) : "v"(a), "v"(b));
    return r;
}
// raw 2^x (hardware v_exp_f32). Args here are <= ~11.5; v_exp(-inf)=0.
__device__ __forceinline__ float vexp2(float x) {
    float r;
    asm("v_exp_f32 %0, %1" : "=v"(r) : "v"(x));
    return r;
}
__device__ __forceinline__ void cvt8(const float4& a, const float4& b, unsigned* t) {
    t[0]=cvt_pk_bf16(a.x,a.y); t[1]=cvt_pk_bf16(a.z,a.w);
    t[2]=cvt_pk_bf16(b.x,b.y); t[3]=cvt_pk_bf16(b.z,b.w);
}

#define GLOAD16(gsrc, ldst)                                                        \
    __builtin_amdgcn_global_load_lds(                                              \
        (const __attribute__((address_space(1))) unsigned int*)(gsrc),             \
        (__attribute__((address_space(3))) unsigned int*)(ldst), 16, 0, 0)

// ---------------------------------------------------------------------------
// Kernel 1: W [C,H] fp32  ->  Wt [t][h][c] bf16  (transposed, cast)
// ---------------------------------------------------------------------------
__global__ __launch_bounds__(256) void wtrans_kernel(
        const float* __restrict__ Wk, const float* __restrict__ Wq,
        const float* __restrict__ Wv, unsigned short* __restrict__ Wt) {
    int tid = blockIdx.x * 256 + threadIdx.x;
    int t = tid >> 17;
    int r = tid & 131071;
    int c = r >> 7;
    int h = r & 127;
    const float* W = (t == 0) ? Wk : (t == 1) ? Wq : Wv;
    Wt[t * 131072 + h * 1024 + c] = f2bf(W[r]);
}

// ---------------------------------------------------------------------------
// Kernel 2: QKV GEMM v5. Block = 64 M x 384 N (ALL of k|q|v), 512 threads
// (8 waves), grid 256 = exactly 1 block/CU. x read ONCE (64 MB total); Wt is
// L2-resident. Double-buffered As+Bs; Bs via swizzled global_load_lds; x
// 2-deep reg prefetch; counted vmcnt 8/6/0. v written directly to vT.
// LDS = 18 + 96 = 114 KB.
// ---------------------------------------------------------------------------
__global__ __launch_bounds__(512, 2) void qkv_gemm5(
        const float* __restrict__ x, const unsigned short* __restrict__ Wt,
        unsigned short* __restrict__ qkv, unsigned short* __restrict__ vT) {
    __shared__ unsigned short As[2][64][72];       // 18.4 KB
    __shared__ unsigned short Bs[2][384][64];      // 96 KB, unpadded+swizzled

    const int nsw = blockIdx.x;
    const int m0 = ((nsw & 7) * 32 + (nsw >> 3)) * 64;   // XCD-contiguous m-bands

    const int tid = threadIdx.x;
    const int lane = tid & 63;
    const int w = tid >> 6;                        // 0..7
    const int fr = lane & 15;
    const int fq = lane >> 4;

    // x staging: thread -> row tid>>3 (64 rows), 8-float column chunk
    const int xrow = tid >> 3, xco = (tid & 7) * 8;
    const float* xsrc = x + (long)(m0 + xrow) * C_ + xco;
    // Bs staging: wave chunk c = w*6+i covers rows 8c..8c+7 (1 KB per chunk)
    const int brl = lane >> 3;
    const int bcolb = (((lane & 7) ^ brl) << 4);
    unsigned short* const bs_flat = &Bs[0][0][0];

    f32x4 acc[3][4];
#pragma unroll
    for (int i = 0; i < 3; i++)
#pragma unroll
        for (int rf = 0; rf < 4; rf++) acc[i][rf] = f32x4{0.f, 0.f, 0.f, 0.f};

    // prologue: x(0) loads, Bs(0) gloads, convert x(0), issue x(1)
    float4 xa0, xa1, xb0, xb1;
    xa0 = ((const float4*)xsrc)[0]; xa1 = ((const float4*)xsrc)[1];
#pragma unroll
    for (int i = 0; i < 6; i++)
        GLOAD16(Wt + (long)(48*w + 8*i + brl) * 1024 + (bcolb >> 1),
                bs_flat + (w*6 + i) * 512);
    {
        unsigned tw[4];
        cvt8(xa0, xa1, tw);
        *(uint4*)&As[0][xrow][xco] = uint4{tw[0], tw[1], tw[2], tw[3]};
    }
    {
        const float* xs = xsrc + 64;
        xa0 = ((const float4*)xs)[0]; xa1 = ((const float4*)xs)[1];
    }

    int cur = 0;
    for (int k = 0; k < 16; ++k) {
        __syncthreads();   // X: all waves done MFMA(k-1); As[cur] visible
        const bool more  = (k + 1) < 16;
        const bool more2 = (k + 2) < 16;
        if (more) {
            if (more2) {
                const float* xs = xsrc + (k + 2) * 64;
                xb0 = ((const float4*)xs)[0]; xb1 = ((const float4*)xs)[1];
            }
            const int boff = (cur ^ 1) * 24576;    // shorts
#pragma unroll
            for (int i = 0; i < 6; i++)
                GLOAD16(Wt + (long)(48*w + 8*i + brl) * 1024 + (k + 1) * 64 + (bcolb >> 1),
                        bs_flat + boff + (w*6 + i) * 512);
            if (more2) asm volatile("s_waitcnt vmcnt(8)" ::: "memory");  // Bs(k) landed
            else       asm volatile("s_waitcnt vmcnt(6)" ::: "memory");
        } else {
            asm volatile("s_waitcnt vmcnt(0)" ::: "memory");
        }
        __syncthreads();   // Y: Bs[cur] visible

        const char* bsb = (const char*)bs_flat + cur * 49152;
        __builtin_amdgcn_s_setprio(1);
#pragma unroll
        for (int kk = 0; kk < 2; kk++) {
            bf16x8 a[4], bb[3];
#pragma unroll
            for (int rf = 0; rf < 4; rf++)
                a[rf] = *(const bf16x8*)&As[cur][rf*16 + fr][kk*32 + fq*8];
#pragma unroll
            for (int i = 0; i < 3; i++) {
                int row = (w*3 + i) * 16 + fr;
                bb[i] = *(const bf16x8*)(bsb + row*128 + ((((kk<<2) + fq) ^ (fr & 7)) << 4));
            }
#pragma unroll
            for (int i = 0; i < 3; i++)
#pragma unroll
                for (int rf = 0; rf < 4; rf++)
                    acc[i][rf] = __builtin_amdgcn_mfma_f32_16x16x32_bf16(
                        a[rf], bb[i], acc[i][rf], 0, 0, 0);
        }
        __builtin_amdgcn_s_setprio(0);

        if (more) {
            unsigned tw[4];
            cvt8(xa0, xa1, tw);
            *(uint4*)&As[cur ^ 1][xrow][xco] = uint4{tw[0], tw[1], tw[2], tw[3]};
            xa0 = xb0; xa1 = xb1;
        }
        cur ^= 1;
    }

    // epilogue: 24 N-frags over 8 waves; t = nfg>>3 (k/q/v), v -> vT
#pragma unroll
    for (int i = 0; i < 3; i++) {
        int nfg = w*3 + i;
        int t = nfg >> 3;
        int col = (nfg & 7) * 16 + fr;
        if (t < 2) {
#pragma unroll
            for (int rf = 0; rf < 4; rf++)
#pragma unroll
                for (int r = 0; r < 4; r++) {
                    int row = m0 + rf*16 + fq*4 + r;
                    qkv[(long)t * 2097152 + (long)row * 128 + col] = f2bf(acc[i][rf][r]);
                }
        } else {
            const int bb_ = m0 >> 12;
            const int trow = m0 & 4095;
#pragma unroll
            for (int rf = 0; rf < 4; rf++) {
                uint2 uu;
                uu.x = cvt_pk_bf16(acc[i][rf][0], acc[i][rf][1]);
                uu.y = cvt_pk_bf16(acc[i][rf][2], acc[i][rf][3]);
                *(uint2*)(vT + ((long)(bb_*128 + col)) * 4096 + trow + rf*16 + fq*4) = uu;
            }
        }
    }
}

// ---------------------------------------------------------------------------
// Kernel 3: flash9 with raw v_exp_f32 softmax (log2-domain scores).
// QB=128, KB=64, split-4, grid 512 = 2 blocks/CU, 1-barrier pipeline, MFMA-l.
// ---------------------------------------------------------------------------
__global__ __launch_bounds__(512, 4) void flash9_kernel(
        const unsigned short* __restrict__ qkv,
        const unsigned short* __restrict__ vT,
        unsigned short* __restrict__ po0, unsigned short* __restrict__ po1,
        unsigned short* __restrict__ po2, unsigned short* __restrict__ po3,
        float* __restrict__ pm, float* __restrict__ pl) {
    __shared__ unsigned short k_lds[2][64][128];
    __shared__ unsigned short v_lds[2][128][64];

    const int n = blockIdx.x;
    const int half = n >> 8;
    const int m = n & 255;
    const int b = (m & 7) >> 1;
    const int r = ((m >> 3) << 1) | (m & 1);
    const int jj = r & 31;
    const int pq = r >> 5;
    const int qt = half ? (31 - jj) : jj;
    const int p = half * 2 + pq;
    const int q0 = qt * 128;
    const int ntt = (qt + 1) * 2;
    const int t0 = (p * ntt) >> 2;
    const int t1 = ((p + 1) * ntt) >> 2;

    const int tid = threadIdx.x;
    const int w = tid >> 6;
    const int lane = tid & 63;
    const int fr = lane & 15;
    const int fq = lane >> 4;

    const unsigned short* kbase = qkv + (long)b * T_ * H_;
    const unsigned short* vbase = vT + (long)b * H_ * T_;

    const int kcolb0 = ((lane & 15) << 4) ^ ((((lane >> 4)) & 7) << 4);
    const int kcolb1 = ((lane & 15) << 4) ^ (((4 + (lane >> 4)) & 7) << 4);
    const int krl = lane >> 4;
    const int vrl = lane >> 3;
    const int vcolb = ((lane & 7) << 4) ^ (vrl << 4);
    unsigned short* const klds_flat = &k_lds[0][0][0];
    unsigned short* const vlds_flat = &v_lds[0][0][0];
    const int scol = ((fq ^ (fr & 7)) << 4);

    bf16x8 qf[4];
    {
        const unsigned short* qptr = qkv + 2097152 + ((long)b*T_ + q0 + w*16 + fr) * H_;
#pragma unroll
        for (int ks = 0; ks < 4; ks++)
            qf[ks] = *(const bf16x8*)(qptr + ks*32 + fq*8);
    }

    bf16x8 ones;
    {
        union { unsigned short s[8]; bf16x8 v; } oc;
#pragma unroll
        for (int i = 0; i < 8; i++) oc.s[i] = 0x3F80;
        ones = oc.v;
    }

    f32x4 acc[8];
#pragma unroll
    for (int i = 0; i < 8; i++) acc[i] = f32x4{0.f, 0.f, 0.f, 0.f};
    f32x4 acc_l = f32x4{0.f, 0.f, 0.f, 0.f};
    float m_r = -INFINITY;
    const int qrow = q0 + w*16 + fr;

    int cur = 0;
    if (t0 < t1) {
        const int kv0 = t0 * 64;
#pragma unroll
        for (int i = 0; i < 2; i++) {
            int kcolb = i ? kcolb1 : kcolb0;
            GLOAD16(kbase + (long)(kv0 + 8*w + 4*i + krl) * 128 + (kcolb >> 1),
                    klds_flat + w*1024 + i*512);
            GLOAD16(vbase + (long)(16*w + 8*i + vrl) * 4096 + kv0 + (vcolb >> 1),
                    vlds_flat + w*1024 + i*512);
        }
    }

    for (int t = t0; t < t1; ++t) {
        const int kv0 = t * 64;
        asm volatile("s_waitcnt vmcnt(0)" ::: "memory");
        __syncthreads();
        if (t + 1 < t1) {
            const int kv0n = kv0 + 64;
            const int boff = (cur ^ 1) * 8192;
#pragma unroll
            for (int i = 0; i < 2; i++) {
                int kcolb = i ? kcolb1 : kcolb0;
                GLOAD16(kbase + (long)(kv0n + 8*w + 4*i + krl) * 128 + (kcolb >> 1),
                        klds_flat + boff + w*1024 + i*512);
                GLOAD16(vbase + (long)(16*w + 8*i + vrl) * 4096 + kv0n + (vcolb >> 1),
                        vlds_flat + boff + w*1024 + i*512);
            }
        }

        const char* kl = (const char*)k_lds + cur*16384 + fr*256;
        const char* vl = (const char*)v_lds + cur*16384 + fr*128;

        f32x4 s[4];
#pragma unroll
        for (int sf = 0; sf < 4; sf++) s[sf] = f32x4{0.f,0.f,0.f,0.f};
        __builtin_amdgcn_s_setprio(1);
#pragma unroll
        for (int sf = 0; sf < 4; sf++)
#pragma unroll
            for (int ks = 0; ks < 4; ks++) {
                bf16x8 kf = *(const bf16x8*)(kl + sf*4096 + (scol ^ (ks << 6)));
                s[sf] = __builtin_amdgcn_mfma_f32_16x16x32_bf16(kf, qf[ks], s[sf], 0, 0, 0);
            }
        __builtin_amdgcn_s_setprio(0);

        // scale (log2 domain) + causal mask + per-lane partial max
        float pmax = -INFINITY;
        if (kv0 + 63 > q0 + 16*w) {
#pragma unroll
            for (int sf = 0; sf < 4; sf++)
#pragma unroll
                for (int rr = 0; rr < 4; rr++) {
                    int kv = kv0 + sf*16 + fq*4 + rr;
                    float sv = s[sf][rr] * SCL2;
                    sv = (kv > qrow) ? -INFINITY : sv;
                    s[sf][rr] = sv;
                    pmax = fmaxf(pmax, sv);
                }
        } else {
#pragma unroll
            for (int sf = 0; sf < 4; sf++)
#pragma unroll
                for (int rr = 0; rr < 4; rr++) {
                    float sv = s[sf][rr] * SCL2;
                    s[sf][rr] = sv;
                    pmax = fmaxf(pmax, sv);
                }
        }

        // defer-max: per-lane check; threshold 8*log2e ~= 11.54
        const bool skip = __all((m_r > -1e37f) & (pmax - m_r <= 11.5f));
        float msub;
        if (skip) {
            msub = m_r;
        } else {
            float mx = fmaxf(pmax, __shfl_xor(pmax, 16, 64));
            mx = fmaxf(mx, __shfl_xor(mx, 32, 64));
            float mn = fmaxf(m_r, mx);
            msub = (mn == -INFINITY) ? 0.f : mn;
            float alpha = vexp2(m_r - msub);
            m_r = mn;
#pragma unroll
            for (int hf = 0; hf < 8; hf++)
#pragma unroll
                for (int rr = 0; rr < 4; rr++) acc[hf][rr] *= alpha;
#pragma unroll
            for (int rr = 0; rr < 4; rr++) acc_l[rr] *= alpha;
        }

        float pv[4][4];
#pragma unroll
        for (int sf = 0; sf < 4; sf++)
#pragma unroll
            for (int rr = 0; rr < 4; rr++)
                pv[sf][rr] = vexp2(s[sf][rr] - msub);

        unsigned pw[8];
#pragma unroll
        for (int sf = 0; sf < 4; sf++) {
            pw[2*sf]   = cvt_pk_bf16(pv[sf][0], pv[sf][1]);
            pw[2*sf+1] = cvt_pk_bf16(pv[sf][2], pv[sf][3]);
        }
        unsigned pbu[2][4];
        pbu[0][0]=0;pbu[0][1]=0;pbu[0][2]=0;pbu[0][3]=0;
        pbu[1][0]=0;pbu[1][1]=0;pbu[1][2]=0;pbu[1][3]=0;
        const int L1 = fr + 16 * ((fq & 1) * 2);
        const int L2 = L1 + 16;
        const int sel = (fq >> 1) & 1;
#pragma unroll
        for (int sf = 0; sf < 4; sf++) {
            unsigned w0 = (unsigned)__shfl((int)pw[2*sf],   L1, 64);
            unsigned w1 = (unsigned)__shfl((int)pw[2*sf+1], L1, 64);
            unsigned w2 = (unsigned)__shfl((int)pw[2*sf],   L2, 64);
            unsigned w3 = (unsigned)__shfl((int)pw[2*sf+1], L2, 64);
            if ((sf & 1) == sel) {
                int k2 = sf >> 1;
                pbu[k2][0] = w0; pbu[k2][1] = w1; pbu[k2][2] = w2; pbu[k2][3] = w3;
            }
        }
        union { unsigned u[4]; bf16x8 v; } pb0c, pb1c;
#pragma unroll
        for (int i = 0; i < 4; i++) { pb0c.u[i] = pbu[0][i]; pb1c.u[i] = pbu[1][i]; }
        bf16x8 pb0 = pb0c.v, pb1 = pb1c.v;

        __builtin_amdgcn_s_setprio(1);
#pragma unroll
        for (int hf = 0; hf < 8; hf++) {
            bf16x8 vf0 = *(const bf16x8*)(vl + hf*2048 + scol);
            bf16x8 vf1 = *(const bf16x8*)(vl + hf*2048 + (scol ^ 64));
            acc[hf] = __builtin_amdgcn_mfma_f32_16x16x32_bf16(vf0, pb0, acc[hf], 0, 0, 0);
            acc[hf] = __builtin_amdgcn_mfma_f32_16x16x32_bf16(vf1, pb1, acc[hf], 0, 0, 0);
        }
        acc_l = __builtin_amdgcn_mfma_f32_16x16x32_bf16(ones, pb0, acc_l, 0, 0, 0);
        acc_l = __builtin_amdgcn_mfma_f32_16x16x32_bf16(ones, pb1, acc_l, 0, 0, 0);
        __builtin_amdgcn_s_setprio(0);
        cur ^= 1;
    }

    unsigned short* po = (p == 0) ? po0 : (p == 1) ? po1 : (p == 2) ? po2 : po3;
    const float l_r = acc_l[0];
    float linv = (l_r > 0.f) ? (1.0f / l_r) : 0.f;
    const long obase = ((long)b * T_ + qrow) * H_;
#pragma unroll
    for (int hf = 0; hf < 8; hf++) {
        uint2 uu;
        uu.x = cvt_pk_bf16(acc[hf][0] * linv, acc[hf][1] * linv);
        uu.y = cvt_pk_bf16(acc[hf][2] * linv, acc[hf][3] * linv);
        *(uint2*)(po + obase + hf*16 + fq*4) = uu;
    }
    if (fq == 0) {
        pm[p * 16384 + b * T_ + qrow] = m_r;   // log2-domain
        pl[p * 16384 + b * T_ + qrow] = l_r;
    }
}

// ---------------------------------------------------------------------------
// Kernel 4: combine the four KV-parts (m in log2 domain -> exp2f)
// ---------------------------------------------------------------------------
__global__ __launch_bounds__(256) void combine4_kernel(
        const unsigned short* __restrict__ po0,
        const unsigned short* __restrict__ po1,
        const unsigned short* __restrict__ po2,
        const unsigned short* __restrict__ po3,
        const float* __restrict__ pm, const float* __restrict__ pl,
        float* __restrict__ out) {
    int idx = blockIdx.x * 256 + threadIdx.x;
    int row = idx >> 4;
    int seg = idx & 15;
    float mv[4], lv[4];
#pragma unroll
    for (int i = 0; i < 4; i++) { mv[i] = pm[i*16384 + row]; lv[i] = pl[i*16384 + row]; }
    float m = fmaxf(fmaxf(mv[0], mv[1]), fmaxf(mv[2], mv[3]));
    float wv[4]; float tot = 0.f;
#pragma unroll
    for (int i = 0; i < 4; i++) {
        wv[i] = (lv[i] > 0.f) ? exp2f(mv[i] - m) * lv[i] : 0.f;
        tot += wv[i];
    }
    float inv = 1.0f / tot;
    long off = (long)row * H_ + seg * 8;
    unsigned short ua[8], ub[8], uc[8], ud[8];
    *(uint4*)ua = *(const uint4*)(po0 + off);
    *(uint4*)ub = *(const uint4*)(po1 + off);
    *(uint4*)uc = *(const uint4*)(po2 + off);
    *(uint4*)ud = *(const uint4*)(po3 + off);
    float* o = out + off;
#pragma unroll
    for (int j2 = 0; j2 < 8; j2++)
        o[j2] = inv * (wv[0] * bf2f(ua[j2]) + wv[1] * bf2f(ub[j2]) +
                       wv[2] * bf2f(uc[j2]) + wv[3] * bf2f(ud[j2]));
}

// ---------------------------------------------------------------------------
extern "C" void kernel_launch(void* const* d_in, const int* in_sizes, int n_in,
                              void* d_out, int out_size, void* d_ws, size_t ws_size,
                              hipStream_t stream) {
    (void)in_sizes; (void)n_in; (void)out_size; (void)ws_size;
    const float* x  = (const float*)d_in[0];
    const float* Wk = (const float*)d_in[1];
    const float* Wq = (const float*)d_in[2];
    const float* Wv = (const float*)d_in[3];
    float* out = (float*)d_out;

    unsigned short* Wt  = (unsigned short*)d_ws;       // 393216 shorts
    unsigned short* qkv = Wt + 393216;                 // k | q | (v slot unused)
    unsigned short* vT  = qkv + 6291456;               // 2097152
    unsigned short* po0 = vT + 2097152;
    unsigned short* po1 = po0 + 2097152;
    unsigned short* po3 = po1 + 2097152;
    unsigned short* po2 = qkv + 4194304;               // aliases unused v slot
    float* pm = (float*)d_ws;                          // 4 x 16384 (alias Wt)
    float* pl = pm + 65536;

    wtrans_kernel<<<1536, 256, 0, stream>>>(Wk, Wq, Wv, Wt);
    qkv_gemm5<<<256, 512, 0, stream>>>(x, Wt, qkv, vT);
    flash9_kernel<<<512, 512, 0, stream>>>(qkv, vT, po0, po1, po2, po3, pm, pl);
    combine4_kernel<<<1024, 256, 0, stream>>>(po0, po1, po2, po3, pm, pl, out);
}

// Round 16
// 78.597 us; speedup vs baseline: 1.0829x; 1.0829x over previous
//
#include <hip/hip_runtime.h>
#include <hip/hip_bf16.h>
#include <math.h>

// Problem constants
#define B_ 4
#define T_ 4096
#define C_ 1024
#define H_ 128
#define SCALE 0.08838834764831845f       // 1/sqrt(128)
#define SCL2  0.12752934464f             // SCALE * log2(e)

typedef __attribute__((ext_vector_type(8))) short bf16x8;
typedef __attribute__((ext_vector_type(4))) float f32x4;

__device__ __forceinline__ unsigned short f2bf(float f) {
    union { float f; unsigned u; } x; x.f = f;
    unsigned r = x.u + 0x7FFF + ((x.u >> 16) & 1);
    return (unsigned short)(r >> 16);
}
__device__ __forceinline__ float bf2f(unsigned short u) {
    union { unsigned u; float f; } x; x.u = ((unsigned)u) << 16;
    return x.f;
}
__device__ __forceinline__ unsigned cvt_pk_bf16(float a, float b) {
    unsigned r;
    asm("v_cvt_pk_bf16_f32 %0, %1, %2" : "=v"(r) : "v"(a), "v"(b));
    return r;
}
// raw 2^x (hardware v_exp_f32). Args here are <= ~11.5; v_exp(-inf)=0.
__device__ __forceinline__ float vexp2(float x) {
    float r;
    asm("v_exp_f32 %0, %1" : "=v"(r) : "v"(x));
    return r;
}
__device__ __forceinline__ void cvt16(const float4& a, const float4& b,
                                      const float4& c, const float4& d,
                                      unsigned* t) {
    t[0]=cvt_pk_bf16(a.x,a.y); t[1]=cvt_pk_bf16(a.z,a.w);
    t[2]=cvt_pk_bf16(b.x,b.y); t[3]=cvt_pk_bf16(b.z,b.w);
    t[4]=cvt_pk_bf16(c.x,c.y); t[5]=cvt_pk_bf16(c.z,c.w);
    t[6]=cvt_pk_bf16(d.x,d.y); t[7]=cvt_pk_bf16(d.z,d.w);
}

#define GLOAD16(gsrc, ldst)                                                        \
    __builtin_amdgcn_global_load_lds(                                              \
        (const __attribute__((address_space(1))) unsigned int*)(gsrc),             \
        (__attribute__((address_space(3))) unsigned int*)(ldst), 16, 0, 0)

// ---------------------------------------------------------------------------
// Kernel 1: W [C,H] fp32  ->  Wt [t][h][c] bf16  (transposed, cast)
// ---------------------------------------------------------------------------
__global__ __launch_bounds__(256) void wtrans_kernel(
        const float* __restrict__ Wk, const float* __restrict__ Wq,
        const float* __restrict__ Wv, unsigned short* __restrict__ Wt) {
    int tid = blockIdx.x * 256 + threadIdx.x;
    int t = tid >> 17;
    int r = tid & 131071;
    int c = r >> 7;
    int h = r & 127;
    const float* W = (t == 0) ? Wk : (t == 1) ? Wq : Wv;
    Wt[t * 131072 + h * 1024 + c] = f2bf(W[r]);
}

// ---------------------------------------------------------------------------
// Kernel 2: QKV GEMM v6 = gemm3 with CU-paired nh-halves. Blocks n and n+256
// share the same m0 (same CU under the 512-grid round-robin, like flash6's
// pairing) and read the same x rows in lockstep -> x fetched from HBM once,
// partner hits L2. Grid 512 (2 blocks/CU), 64M x 192N, double-buffered,
// Bs via swizzled global_load_lds, x 2-deep reg prefetch, vmcnt 10/6/0.
// ---------------------------------------------------------------------------
__global__ __launch_bounds__(256, 2) void qkv_gemm6(
        const float* __restrict__ x, const unsigned short* __restrict__ Wt,
        unsigned short* __restrict__ qkv, unsigned short* __restrict__ vT) {
    __shared__ unsigned short As[2][64][72];
    __shared__ unsigned short Bs[2][192][64];

    const int n = blockIdx.x;
    const int mm = n & 255;
    const int nh = n >> 8;                        // 0 or 1 (pair halves)
    const int m0 = ((mm & 7) * 32 + (mm >> 3)) * 64;   // XCD-contiguous m-bands

    const int tid = threadIdx.x;
    const int lane = tid & 63;
    const int w = tid >> 6;
    const int fr = lane & 15;
    const int fq = lane >> 4;

    const int xrow = tid >> 2, xco = (tid & 3) * 16;
    const float* xsrc = x + (long)(m0 + xrow) * C_ + xco;
    const int brl = lane >> 3;
    const int bcolb = (((lane & 7) ^ brl) << 4);
    unsigned short* const bs_flat = &Bs[0][0][0];
    const unsigned short* wbase = Wt + (long)(nh * 192) * 1024;

    f32x4 acc[3][4];
#pragma unroll
    for (int i = 0; i < 3; i++)
#pragma unroll
        for (int rf = 0; rf < 4; rf++) acc[i][rf] = f32x4{0.f, 0.f, 0.f, 0.f};

    // prologue: x(0), Bs(0), convert x(0) -> As[0], then issue x(1)
    float4 xa0, xa1, xa2, xa3, xb0, xb1, xb2, xb3;
    xa0 = ((const float4*)xsrc)[0]; xa1 = ((const float4*)xsrc)[1];
    xa2 = ((const float4*)xsrc)[2]; xa3 = ((const float4*)xsrc)[3];
#pragma unroll
    for (int i = 0; i < 6; i++)
        GLOAD16(wbase + (long)(48*w + 8*i + brl) * 1024 + (bcolb >> 1),
                bs_flat + (w*6 + i) * 512);
    {
        unsigned tw[8];
        cvt16(xa0, xa1, xa2, xa3, tw);
        *(uint4*)&As[0][xrow][xco]     = uint4{tw[0], tw[1], tw[2], tw[3]};
        *(uint4*)&As[0][xrow][xco + 8] = uint4{tw[4], tw[5], tw[6], tw[7]};
    }
    {
        const float* xs = xsrc + 64;
        xa0 = ((const float4*)xs)[0]; xa1 = ((const float4*)xs)[1];
        xa2 = ((const float4*)xs)[2]; xa3 = ((const float4*)xs)[3];
    }

    int cur = 0;
    for (int k = 0; k < 16; ++k) {
        __syncthreads();   // X
        const bool more  = (k + 1) < 16;
        const bool more2 = (k + 2) < 16;
        if (more) {
            if (more2) {
                const float* xs = xsrc + (k + 2) * 64;
                xb0 = ((const float4*)xs)[0]; xb1 = ((const float4*)xs)[1];
                xb2 = ((const float4*)xs)[2]; xb3 = ((const float4*)xs)[3];
            }
            const int boff = (cur ^ 1) * 12288;
#pragma unroll
            for (int i = 0; i < 6; i++)
                GLOAD16(wbase + (long)(48*w + 8*i + brl) * 1024 + (k + 1) * 64 + (bcolb >> 1),
                        bs_flat + boff + (w*6 + i) * 512);
            if (more2) asm volatile("s_waitcnt vmcnt(10)" ::: "memory");
            else       asm volatile("s_waitcnt vmcnt(6)" ::: "memory");
        } else {
            asm volatile("s_waitcnt vmcnt(0)" ::: "memory");
        }
        __syncthreads();   // Y

        const char* bsb = (const char*)bs_flat + cur * 24576;
        __builtin_amdgcn_s_setprio(1);
#pragma unroll
        for (int kk = 0; kk < 2; kk++) {
            bf16x8 a[4], bb[3];
#pragma unroll
            for (int rf = 0; rf < 4; rf++)
                a[rf] = *(const bf16x8*)&As[cur][rf*16 + fr][kk*32 + fq*8];
#pragma unroll
            for (int i = 0; i < 3; i++) {
                int row = (w*3 + i) * 16 + fr;
                bb[i] = *(const bf16x8*)(bsb + row*128 + ((((kk<<2) + fq) ^ (fr & 7)) << 4));
            }
#pragma unroll
            for (int i = 0; i < 3; i++)
#pragma unroll
                for (int rf = 0; rf < 4; rf++)
                    acc[i][rf] = __builtin_amdgcn_mfma_f32_16x16x32_bf16(
                        a[rf], bb[i], acc[i][rf], 0, 0, 0);
        }
        __builtin_amdgcn_s_setprio(0);

        if (more) {
            unsigned tw[8];
            cvt16(xa0, xa1, xa2, xa3, tw);
            *(uint4*)&As[cur ^ 1][xrow][xco]     = uint4{tw[0], tw[1], tw[2], tw[3]};
            *(uint4*)&As[cur ^ 1][xrow][xco + 8] = uint4{tw[4], tw[5], tw[6], tw[7]};
            xa0 = xb0; xa1 = xb1; xa2 = xb2; xa3 = xb3;
        }
        cur ^= 1;
    }

    // epilogue
#pragma unroll
    for (int i = 0; i < 3; i++) {
        int nfg = nh*12 + w*3 + i;
        int t = nfg >> 3;
        int col = (nfg & 7) * 16 + fr;
        if (t < 2) {
#pragma unroll
            for (int rf = 0; rf < 4; rf++)
#pragma unroll
                for (int r = 0; r < 4; r++) {
                    int row = m0 + rf*16 + fq*4 + r;
                    qkv[(long)t * 2097152 + (long)row * 128 + col] = f2bf(acc[i][rf][r]);
                }
        } else {
            const int bb_ = m0 >> 12;
            const int trow = m0 & 4095;
#pragma unroll
            for (int rf = 0; rf < 4; rf++) {
                uint2 uu;
                uu.x = cvt_pk_bf16(acc[i][rf][0], acc[i][rf][1]);
                uu.y = cvt_pk_bf16(acc[i][rf][2], acc[i][rf][3]);
                *(uint2*)(vT + ((long)(bb_*128 + col)) * 4096 + trow + rf*16 + fq*4) = uu;
            }
        }
    }
}

// ---------------------------------------------------------------------------
// Kernel 3: flash9 with raw v_exp_f32 softmax (log2-domain scores).
// QB=128, KB=64, split-4, grid 512 = 2 blocks/CU, 1-barrier pipeline, MFMA-l.
// ---------------------------------------------------------------------------
__global__ __launch_bounds__(512, 4) void flash9_kernel(
        const unsigned short* __restrict__ qkv,
        const unsigned short* __restrict__ vT,
        unsigned short* __restrict__ po0, unsigned short* __restrict__ po1,
        unsigned short* __restrict__ po2, unsigned short* __restrict__ po3,
        float* __restrict__ pm, float* __restrict__ pl) {
    __shared__ unsigned short k_lds[2][64][128];
    __shared__ unsigned short v_lds[2][128][64];

    const int n = blockIdx.x;
    const int half = n >> 8;
    const int m = n & 255;
    const int b = (m & 7) >> 1;
    const int r = ((m >> 3) << 1) | (m & 1);
    const int jj = r & 31;
    const int pq = r >> 5;
    const int qt = half ? (31 - jj) : jj;
    const int p = half * 2 + pq;
    const int q0 = qt * 128;
    const int ntt = (qt + 1) * 2;
    const int t0 = (p * ntt) >> 2;
    const int t1 = ((p + 1) * ntt) >> 2;

    const int tid = threadIdx.x;
    const int w = tid >> 6;
    const int lane = tid & 63;
    const int fr = lane & 15;
    const int fq = lane >> 4;

    const unsigned short* kbase = qkv + (long)b * T_ * H_;
    const unsigned short* vbase = vT + (long)b * H_ * T_;

    const int kcolb0 = ((lane & 15) << 4) ^ ((((lane >> 4)) & 7) << 4);
    const int kcolb1 = ((lane & 15) << 4) ^ (((4 + (lane >> 4)) & 7) << 4);
    const int krl = lane >> 4;
    const int vrl = lane >> 3;
    const int vcolb = ((lane & 7) << 4) ^ (vrl << 4);
    unsigned short* const klds_flat = &k_lds[0][0][0];
    unsigned short* const vlds_flat = &v_lds[0][0][0];
    const int scol = ((fq ^ (fr & 7)) << 4);

    bf16x8 qf[4];
    {
        const unsigned short* qptr = qkv + 2097152 + ((long)b*T_ + q0 + w*16 + fr) * H_;
#pragma unroll
        for (int ks = 0; ks < 4; ks++)
            qf[ks] = *(const bf16x8*)(qptr + ks*32 + fq*8);
    }

    bf16x8 ones;
    {
        union { unsigned short s[8]; bf16x8 v; } oc;
#pragma unroll
        for (int i = 0; i < 8; i++) oc.s[i] = 0x3F80;
        ones = oc.v;
    }

    f32x4 acc[8];
#pragma unroll
    for (int i = 0; i < 8; i++) acc[i] = f32x4{0.f, 0.f, 0.f, 0.f};
    f32x4 acc_l = f32x4{0.f, 0.f, 0.f, 0.f};
    float m_r = -INFINITY;
    const int qrow = q0 + w*16 + fr;

    int cur = 0;
    if (t0 < t1) {
        const int kv0 = t0 * 64;
#pragma unroll
        for (int i = 0; i < 2; i++) {
            int kcolb = i ? kcolb1 : kcolb0;
            GLOAD16(kbase + (long)(kv0 + 8*w + 4*i + krl) * 128 + (kcolb >> 1),
                    klds_flat + w*1024 + i*512);
            GLOAD16(vbase + (long)(16*w + 8*i + vrl) * 4096 + kv0 + (vcolb >> 1),
                    vlds_flat + w*1024 + i*512);
        }
    }

    for (int t = t0; t < t1; ++t) {
        const int kv0 = t * 64;
        asm volatile("s_waitcnt vmcnt(0)" ::: "memory");
        __syncthreads();
        if (t + 1 < t1) {
            const int kv0n = kv0 + 64;
            const int boff = (cur ^ 1) * 8192;
#pragma unroll
            for (int i = 0; i < 2; i++) {
                int kcolb = i ? kcolb1 : kcolb0;
                GLOAD16(kbase + (long)(kv0n + 8*w + 4*i + krl) * 128 + (kcolb >> 1),
                        klds_flat + boff + w*1024 + i*512);
                GLOAD16(vbase + (long)(16*w + 8*i + vrl) * 4096 + kv0n + (vcolb >> 1),
                        vlds_flat + boff + w*1024 + i*512);
            }
        }

        const char* kl = (const char*)k_lds + cur*16384 + fr*256;
        const char* vl = (const char*)v_lds + cur*16384 + fr*128;

        f32x4 s[4];
#pragma unroll
        for (int sf = 0; sf < 4; sf++) s[sf] = f32x4{0.f,0.f,0.f,0.f};
        __builtin_amdgcn_s_setprio(1);
#pragma unroll
        for (int sf = 0; sf < 4; sf++)
#pragma unroll
            for (int ks = 0; ks < 4; ks++) {
                bf16x8 kf = *(const bf16x8*)(kl + sf*4096 + (scol ^ (ks << 6)));
                s[sf] = __builtin_amdgcn_mfma_f32_16x16x32_bf16(kf, qf[ks], s[sf], 0, 0, 0);
            }
        __builtin_amdgcn_s_setprio(0);

        float pmax = -INFINITY;
        if (kv0 + 63 > q0 + 16*w) {
#pragma unroll
            for (int sf = 0; sf < 4; sf++)
#pragma unroll
                for (int rr = 0; rr < 4; rr++) {
                    int kv = kv0 + sf*16 + fq*4 + rr;
                    float sv = s[sf][rr] * SCL2;
                    sv = (kv > qrow) ? -INFINITY : sv;
                    s[sf][rr] = sv;
                    pmax = fmaxf(pmax, sv);
                }
        } else {
#pragma unroll
            for (int sf = 0; sf < 4; sf++)
#pragma unroll
                for (int rr = 0; rr < 4; rr++) {
                    float sv = s[sf][rr] * SCL2;
                    s[sf][rr] = sv;
                    pmax = fmaxf(pmax, sv);
                }
        }

        const bool skip = __all((m_r > -1e37f) & (pmax - m_r <= 11.5f));
        float msub;
        if (skip) {
            msub = m_r;
        } else {
            float mx = fmaxf(pmax, __shfl_xor(pmax, 16, 64));
            mx = fmaxf(mx, __shfl_xor(mx, 32, 64));
            float mn = fmaxf(m_r, mx);
            msub = (mn == -INFINITY) ? 0.f : mn;
            float alpha = vexp2(m_r - msub);
            m_r = mn;
#pragma unroll
            for (int hf = 0; hf < 8; hf++)
#pragma unroll
                for (int rr = 0; rr < 4; rr++) acc[hf][rr] *= alpha;
#pragma unroll
            for (int rr = 0; rr < 4; rr++) acc_l[rr] *= alpha;
        }

        float pv[4][4];
#pragma unroll
        for (int sf = 0; sf < 4; sf++)
#pragma unroll
            for (int rr = 0; rr < 4; rr++)
                pv[sf][rr] = vexp2(s[sf][rr] - msub);

        unsigned pw[8];
#pragma unroll
        for (int sf = 0; sf < 4; sf++) {
            pw[2*sf]   = cvt_pk_bf16(pv[sf][0], pv[sf][1]);
            pw[2*sf+1] = cvt_pk_bf16(pv[sf][2], pv[sf][3]);
        }
        unsigned pbu[2][4];
        pbu[0][0]=0;pbu[0][1]=0;pbu[0][2]=0;pbu[0][3]=0;
        pbu[1][0]=0;pbu[1][1]=0;pbu[1][2]=0;pbu[1][3]=0;
        const int L1 = fr + 16 * ((fq & 1) * 2);
        const int L2 = L1 + 16;
        const int sel = (fq >> 1) & 1;
#pragma unroll
        for (int sf = 0; sf < 4; sf++) {
            unsigned w0 = (unsigned)__shfl((int)pw[2*sf],   L1, 64);
            unsigned w1 = (unsigned)__shfl((int)pw[2*sf+1], L1, 64);
            unsigned w2 = (unsigned)__shfl((int)pw[2*sf],   L2, 64);
            unsigned w3 = (unsigned)__shfl((int)pw[2*sf+1], L2, 64);
            if ((sf & 1) == sel) {
                int k2 = sf >> 1;
                pbu[k2][0] = w0; pbu[k2][1] = w1; pbu[k2][2] = w2; pbu[k2][3] = w3;
            }
        }
        union { unsigned u[4]; bf16x8 v; } pb0c, pb1c;
#pragma unroll
        for (int i = 0; i < 4; i++) { pb0c.u[i] = pbu[0][i]; pb1c.u[i] = pbu[1][i]; }
        bf16x8 pb0 = pb0c.v, pb1 = pb1c.v;

        __builtin_amdgcn_s_setprio(1);
#pragma unroll
        for (int hf = 0; hf < 8; hf++) {
            bf16x8 vf0 = *(const bf16x8*)(vl + hf*2048 + scol);
            bf16x8 vf1 = *(const bf16x8*)(vl + hf*2048 + (scol ^ 64));
            acc[hf] = __builtin_amdgcn_mfma_f32_16x16x32_bf16(vf0, pb0, acc[hf], 0, 0, 0);
            acc[hf] = __builtin_amdgcn_mfma_f32_16x16x32_bf16(vf1, pb1, acc[hf], 0, 0, 0);
        }
        acc_l = __builtin_amdgcn_mfma_f32_16x16x32_bf16(ones, pb0, acc_l, 0, 0, 0);
        acc_l = __builtin_amdgcn_mfma_f32_16x16x32_bf16(ones, pb1, acc_l, 0, 0, 0);
        __builtin_amdgcn_s_setprio(0);
        cur ^= 1;
    }

    unsigned short* po = (p == 0) ? po0 : (p == 1) ? po1 : (p == 2) ? po2 : po3;
    const float l_r = acc_l[0];
    float linv = (l_r > 0.f) ? (1.0f / l_r) : 0.f;
    const long obase = ((long)b * T_ + qrow) * H_;
#pragma unroll
    for (int hf = 0; hf < 8; hf++) {
        uint2 uu;
        uu.x = cvt_pk_bf16(acc[hf][0] * linv, acc[hf][1] * linv);
        uu.y = cvt_pk_bf16(acc[hf][2] * linv, acc[hf][3] * linv);
        *(uint2*)(po + obase + hf*16 + fq*4) = uu;
    }
    if (fq == 0) {
        pm[p * 16384 + b * T_ + qrow] = m_r;   // log2-domain
        pl[p * 16384 + b * T_ + qrow] = l_r;
    }
}

// ---------------------------------------------------------------------------
// Kernel 4: combine the four KV-parts (m in log2 domain -> exp2f)
// ---------------------------------------------------------------------------
__global__ __launch_bounds__(256) void combine4_kernel(
        const unsigned short* __restrict__ po0,
        const unsigned short* __restrict__ po1,
        const unsigned short* __restrict__ po2,
        const unsigned short* __restrict__ po3,
        const float* __restrict__ pm, const float* __restrict__ pl,
        float* __restrict__ out) {
    int idx = blockIdx.x * 256 + threadIdx.x;
    int row = idx >> 4;
    int seg = idx & 15;
    float mv[4], lv[4];
#pragma unroll
    for (int i = 0; i < 4; i++) { mv[i] = pm[i*16384 + row]; lv[i] = pl[i*16384 + row]; }
    float m = fmaxf(fmaxf(mv[0], mv[1]), fmaxf(mv[2], mv[3]));
    float wv[4]; float tot = 0.f;
#pragma unroll
    for (int i = 0; i < 4; i++) {
        wv[i] = (lv[i] > 0.f) ? exp2f(mv[i] - m) * lv[i] : 0.f;
        tot += wv[i];
    }
    float inv = 1.0f / tot;
    long off = (long)row * H_ + seg * 8;
    unsigned short ua[8], ub[8], uc[8], ud[8];
    *(uint4*)ua = *(const uint4*)(po0 + off);
    *(uint4*)ub = *(const uint4*)(po1 + off);
    *(uint4*)uc = *(const uint4*)(po2 + off);
    *(uint4*)ud = *(const uint4*)(po3 + off);
    float* o = out + off;
#pragma unroll
    for (int j2 = 0; j2 < 8; j2++)
        o[j2] = inv * (wv[0] * bf2f(ua[j2]) + wv[1] * bf2f(ub[j2]) +
                       wv[2] * bf2f(uc[j2]) + wv[3] * bf2f(ud[j2]));
}

// ---------------------------------------------------------------------------
extern "C" void kernel_launch(void* const* d_in, const int* in_sizes, int n_in,
                              void* d_out, int out_size, void* d_ws, size_t ws_size,
                              hipStream_t stream) {
    (void)in_sizes; (void)n_in; (void)out_size; (void)ws_size;
    const float* x  = (const float*)d_in[0];
    const float* Wk = (const float*)d_in[1];
    const float* Wq = (const float*)d_in[2];
    const float* Wv = (const float*)d_in[3];
    float* out = (float*)d_out;

    unsigned short* Wt  = (unsigned short*)d_ws;       // 393216 shorts
    unsigned short* qkv = Wt + 393216;                 // k | q | (v slot unused)
    unsigned short* vT  = qkv + 6291456;               // 2097152
    unsigned short* po0 = vT + 2097152;
    unsigned short* po1 = po0 + 2097152;
    unsigned short* po3 = po1 + 2097152;
    unsigned short* po2 = qkv + 4194304;               // aliases unused v slot
    float* pm = (float*)d_ws;                          // 4 x 16384 (alias Wt)
    float* pl = pm + 65536;

    wtrans_kernel<<<1536, 256, 0, stream>>>(Wk, Wq, Wv, Wt);
    qkv_gemm6<<<512, 256, 0, stream>>>(x, Wt, qkv, vT);
    flash9_kernel<<<512, 512, 0, stream>>>(qkv, vT, po0, po1, po2, po3, pm, pl);
    combine4_kernel<<<1024, 256, 0, stream>>>(po0, po1, po2, po3, pm, pl, out);
}